// Round 1
// baseline (783.464 us; speedup 1.0000x reference)
//
#include <hip/hip_runtime.h>

// RoIAlign3D: features (N=2,C=128,D=24,H=128,W=128) f32, rois (256,7) f32
// out (R=256,C=128,OUT_D=4,OUT=7,OUT=7) f32, SN=2 samples/axis, mean-pooled.

#define N_   2
#define C_   128
#define D_   24
#define H_   128
#define W_   128
#define OUTD 4
#define OUTHW 7

__device__ __forceinline__ void axis_sample(float coord, int dim,
                                            int& lo, int& hi,
                                            float& wlo, float& whi) {
    // mirror of reference _axis(): valid strict (>-1, <dim), clip, floor, frac
    bool valid = (coord > -1.0f) && (coord < (float)dim);
    float c = fminf(fmaxf(coord, 0.0f), (float)(dim - 1));
    int l = (int)floorf(c);
    l = min(l, dim - 1);
    int h = min(l + 1, dim - 1);
    float f = c - (float)l;
    float v = valid ? 1.0f : 0.0f;
    lo = l; hi = h;
    wlo = (1.0f - f) * v;
    whi = f * v;
}

__global__ __launch_bounds__(256) void roialign3d_kernel(
    const float* __restrict__ feat,   // (N,C,D,H,W)
    const float* __restrict__ rois,   // (R,7)
    float* __restrict__ out,          // (R,C,OUTD,OUT,OUT)
    int total)
{
    unsigned idx = blockIdx.x * 256u + threadIdx.x;
    if ((int)idx >= total) return;

    // decode in output order: pw innermost -> coalesced stores,
    // wave lanes share (r,c) spatial footprint -> cache-line reuse.
    unsigned t = idx;
    int pw = t % 7u;  t /= 7u;
    int ph = t % 7u;  t /= 7u;
    int pd = t % 4u;  t /= 4u;
    int c  = t % 128u;
    int r  = t / 128u;

    const float* roi = rois + r * 7;
    int   bi = (int)roi[0];
    float x1 = roi[1] * 0.125f;
    float y1 = roi[2] * 0.125f;
    float x2 = roi[3] * 0.125f;
    float y2 = roi[4] * 0.125f;
    float z1 = roi[5] * 0.25f;
    float z2 = roi[6] * 0.25f;
    float bw = fmaxf(x2 - x1, 1.0f) * (1.0f / 7.0f);
    float bh = fmaxf(y2 - y1, 1.0f) * (1.0f / 7.0f);
    float bd = fmaxf(z2 - z1, 1.0f) * (1.0f / 4.0f);

    // per-axis: 2 samples -> 4 (index, weight) pairs each
    int   zi_[4], yi_[4], xi_[4];
    float zw_[4], yw_[4], xw_[4];
#pragma unroll
    for (int s = 0; s < 2; ++s) {
        float off = (s == 0) ? 0.25f : 0.75f;   // (s+0.5)/SN
        int lo, hi; float wl, wh;

        axis_sample(z1 + ((float)pd + off) * bd, D_, lo, hi, wl, wh);
        zi_[2*s] = lo; zw_[2*s] = wl; zi_[2*s+1] = hi; zw_[2*s+1] = wh;

        axis_sample(y1 + ((float)ph + off) * bh, H_, lo, hi, wl, wh);
        yi_[2*s] = lo; yw_[2*s] = wl; yi_[2*s+1] = hi; yw_[2*s+1] = wh;

        axis_sample(x1 + ((float)pw + off) * bw, W_, lo, hi, wl, wh);
        xi_[2*s] = lo; xw_[2*s] = wl; xi_[2*s+1] = hi; xw_[2*s+1] = wh;
    }

    const float* fbase = feat + ((size_t)bi * C_ + c) * (size_t)(D_ * H_ * W_);

    float acc = 0.0f;
#pragma unroll
    for (int i = 0; i < 4; ++i) {
        float wz = zw_[i];
        if (wz != 0.0f) {
            int zo = zi_[i] * (H_ * W_);
#pragma unroll
            for (int j = 0; j < 4; ++j) {
                float wzy = wz * yw_[j];
                if (wzy != 0.0f) {
                    const float* row = fbase + zo + yi_[j] * W_;
                    float rs;
                    rs  = xw_[0] * row[xi_[0]];
                    rs += xw_[1] * row[xi_[1]];
                    rs += xw_[2] * row[xi_[2]];
                    rs += xw_[3] * row[xi_[3]];
                    acc += wzy * rs;
                }
            }
        }
    }

    out[idx] = acc * 0.125f;   // mean over SN^3 = 8 samples
}

extern "C" void kernel_launch(void* const* d_in, const int* in_sizes, int n_in,
                              void* d_out, int out_size, void* d_ws, size_t ws_size,
                              hipStream_t stream) {
    const float* feat = (const float*)d_in[0];
    const float* rois = (const float*)d_in[1];
    float* out = (float*)d_out;

    int total = out_size;                 // 256*128*4*7*7 = 6,422,528
    int blocks = (total + 255) / 256;     // 25088

    hipLaunchKernelGGL(roialign3d_kernel, dim3(blocks), dim3(256), 0, stream,
                       feat, rois, out, total);
}

// Round 4
// 668.008 us; speedup vs baseline: 1.1728x; 1.1728x over previous
//
#include <hip/hip_runtime.h>
#include <hip/hip_fp16.h>

// RoIAlign3D: features (N=2,C=128,D=24,H=128,W=128) f32, rois (256,7) f32
// out (R=256,C=128,4,7,7) f32.
// Phase 1: transpose features to channels-last fp16 in d_ws: ft[(n,z,y,x), c]
// Phase 2: gather — 16 lanes per output cell, lane = 8 channels (16B loads).

#define N_   2
#define C_   128
#define D_   24
#define H_   128
#define W_   128
#define HW_  (H_ * W_)           // 16384
#define DHW_ (D_ * H_ * W_)      // 393216
#define NVOX (N_ * D_ * H_ * W_) // 786432
#define CELLS (256 * 4 * 7 * 7)  // 50176

__device__ __forceinline__ void axis_sample(float coord, int dim,
                                            int& lo, int& hi,
                                            float& wlo, float& whi) {
    bool valid = (coord > -1.0f) && (coord < (float)dim);
    float c = fminf(fmaxf(coord, 0.0f), (float)(dim - 1));
    int l = (int)floorf(c);
    l = min(l, dim - 1);
    int h = min(l + 1, dim - 1);
    float f = c - (float)l;
    float v = valid ? 1.0f : 0.0f;
    lo = l; hi = h;
    wlo = (1.0f - f) * v;
    whi = f * v;
}

// ---------------- Phase 1: NCDHW f32 -> (N,D,H,W,C) fp16 ----------------
// grid: N*D*H*(W/16) blocks of 256. Tile: 128 channels x 16 x-positions.
__global__ __launch_bounds__(256) void transpose_chlast_fp16(
    const float* __restrict__ feat, unsigned short* __restrict__ ft)
{
    __shared__ unsigned short lds[16][132];   // [x][c], padded stride

    int b  = blockIdx.x;
    int xt = b & 7;              // x-tile (16 wide)
    int y  = (b >> 3) & 127;
    int zn = b >> 10;            // 0..47
    int z  = zn % 24;
    int n  = zn / 24;

    int t  = threadIdx.x;
    int x  = t & 15;
    int c0 = t >> 4;             // 0..15

    const float* src = feat + (size_t)(n * C_) * DHW_ + (size_t)z * HW_
                            + y * W_ + xt * 16 + x;
#pragma unroll
    for (int p = 0; p < 8; ++p) {
        int c = c0 + (p << 4);
        float v = src[(size_t)c * DHW_];
        lds[x][c] = __half_as_ushort(__float2half_rn(v));
    }
    __syncthreads();

    // write: per voxel, 128 channels contiguous (256B). lane = ushort2 (2 ch).
    int c2  = t & 63;
    int xx0 = t >> 6;            // 0..3
    size_t vox_base = (((size_t)(n * 24 + z) * 128 + y) * 128) + xt * 16;
    ushort2* dst = (ushort2*)ft;
#pragma unroll
    for (int q = 0; q < 4; ++q) {
        int xx = xx0 + (q << 2);
        ushort2 val;
        val.x = lds[xx][2 * c2];
        val.y = lds[xx][2 * c2 + 1];
        dst[(vox_base + xx) * 64 + c2] = val;
    }
}

// ---------------- Phase 2: gather from channels-last fp16 ----------------
// thread t: lane = t&15 (8 channels each), cell = t>>4.
__global__ __launch_bounds__(256) void roialign_gather_fp16(
    const unsigned short* __restrict__ ft, const float* __restrict__ rois,
    float* __restrict__ out)
{
    int t = blockIdx.x * 256 + threadIdx.x;
    int lane = t & 15;
    int cell = t >> 4;
    if (cell >= CELLS) return;

    int pw = cell % 7;
    int ph = (cell / 7) % 7;
    int pd = (cell / 49) % 4;
    int r  = cell / 196;

    const float* roi = rois + r * 7;
    int   bi = (int)roi[0];
    float x1 = roi[1] * 0.125f;
    float y1 = roi[2] * 0.125f;
    float x2 = roi[3] * 0.125f;
    float y2 = roi[4] * 0.125f;
    float z1 = roi[5] * 0.25f;
    float z2 = roi[6] * 0.25f;
    float bw = fmaxf(x2 - x1, 1.0f) * (1.0f / 7.0f);
    float bh = fmaxf(y2 - y1, 1.0f) * (1.0f / 7.0f);
    float bd = fmaxf(z2 - z1, 1.0f) * (1.0f / 4.0f);

    int   zi_[4], yi_[4], xi_[4];
    float zw_[4], yw_[4], xw_[4];
#pragma unroll
    for (int s = 0; s < 2; ++s) {
        float off = (s == 0) ? 0.25f : 0.75f;
        int lo, hi; float wl, wh;

        axis_sample(z1 + ((float)pd + off) * bd, D_, lo, hi, wl, wh);
        zi_[2*s] = lo; zw_[2*s] = wl; zi_[2*s+1] = hi; zw_[2*s+1] = wh;

        axis_sample(y1 + ((float)ph + off) * bh, H_, lo, hi, wl, wh);
        yi_[2*s] = lo; yw_[2*s] = wl; yi_[2*s+1] = hi; yw_[2*s+1] = wh;

        axis_sample(x1 + ((float)pw + off) * bw, W_, lo, hi, wl, wh);
        xi_[2*s] = lo; xw_[2*s] = wl; xi_[2*s+1] = hi; xw_[2*s+1] = wh;
    }

    float acc[8] = {0.f, 0.f, 0.f, 0.f, 0.f, 0.f, 0.f, 0.f};
    const unsigned short* basep = ft + (lane << 3);

#pragma unroll
    for (int i = 0; i < 4; ++i) {
        int zrow = (bi * D_ + zi_[i]) * H_;
        float wz = zw_[i];
#pragma unroll
        for (int j = 0; j < 4; ++j) {
            float wzy = wz * yw_[j];
            int yrow = (zrow + yi_[j]) * W_;
#pragma unroll
            for (int k = 0; k < 4; ++k) {
                float w = wzy * xw_[k];
                const unsigned short* p = basep + ((size_t)(yrow + xi_[k]) << 7);
                uint4 u = *reinterpret_cast<const uint4*>(p);
                float2 f0 = __half22float2(*reinterpret_cast<__half2*>(&u.x));
                float2 f1 = __half22float2(*reinterpret_cast<__half2*>(&u.y));
                float2 f2 = __half22float2(*reinterpret_cast<__half2*>(&u.z));
                float2 f3 = __half22float2(*reinterpret_cast<__half2*>(&u.w));
                acc[0] = fmaf(w, f0.x, acc[0]);
                acc[1] = fmaf(w, f0.y, acc[1]);
                acc[2] = fmaf(w, f1.x, acc[2]);
                acc[3] = fmaf(w, f1.y, acc[3]);
                acc[4] = fmaf(w, f2.x, acc[4]);
                acc[5] = fmaf(w, f2.y, acc[5]);
                acc[6] = fmaf(w, f3.x, acc[6]);
                acc[7] = fmaf(w, f3.y, acc[7]);
            }
        }
    }

    int sp = (pd * 49 + ph * 7 + pw);
    size_t ob = ((size_t)r * 128 + (lane << 3)) * 196 + sp;
#pragma unroll
    for (int j = 0; j < 8; ++j)
        out[ob + (size_t)j * 196] = acc[j] * 0.125f;
}

// ---------------- Fallback (round-1 kernel) if ws too small ----------------
__global__ __launch_bounds__(256) void roialign3d_direct(
    const float* __restrict__ feat, const float* __restrict__ rois,
    float* __restrict__ out, int total)
{
    unsigned idx = blockIdx.x * 256u + threadIdx.x;
    if ((int)idx >= total) return;
    unsigned t = idx;
    int pw = t % 7u;  t /= 7u;
    int ph = t % 7u;  t /= 7u;
    int pd = t % 4u;  t /= 4u;
    int c  = t % 128u;
    int r  = t / 128u;

    const float* roi = rois + r * 7;
    int   bi = (int)roi[0];
    float x1 = roi[1] * 0.125f, y1 = roi[2] * 0.125f;
    float x2 = roi[3] * 0.125f, y2 = roi[4] * 0.125f;
    float z1 = roi[5] * 0.25f,  z2 = roi[6] * 0.25f;
    float bw = fmaxf(x2 - x1, 1.0f) * (1.0f / 7.0f);
    float bh = fmaxf(y2 - y1, 1.0f) * (1.0f / 7.0f);
    float bd = fmaxf(z2 - z1, 1.0f) * (1.0f / 4.0f);

    int   zi_[4], yi_[4], xi_[4];
    float zw_[4], yw_[4], xw_[4];
#pragma unroll
    for (int s = 0; s < 2; ++s) {
        float off = (s == 0) ? 0.25f : 0.75f;
        int lo, hi; float wl, wh;
        axis_sample(z1 + ((float)pd + off) * bd, D_, lo, hi, wl, wh);
        zi_[2*s] = lo; zw_[2*s] = wl; zi_[2*s+1] = hi; zw_[2*s+1] = wh;
        axis_sample(y1 + ((float)ph + off) * bh, H_, lo, hi, wl, wh);
        yi_[2*s] = lo; yw_[2*s] = wl; yi_[2*s+1] = hi; yw_[2*s+1] = wh;
        axis_sample(x1 + ((float)pw + off) * bw, W_, lo, hi, wl, wh);
        xi_[2*s] = lo; xw_[2*s] = wl; xi_[2*s+1] = hi; xw_[2*s+1] = wh;
    }

    const float* fbase = feat + ((size_t)bi * C_ + c) * (size_t)DHW_;
    float acc = 0.0f;
#pragma unroll
    for (int i = 0; i < 4; ++i) {
        float wz = zw_[i];
        if (wz != 0.0f) {
            int zo = zi_[i] * HW_;
#pragma unroll
            for (int j = 0; j < 4; ++j) {
                float wzy = wz * yw_[j];
                if (wzy != 0.0f) {
                    const float* row = fbase + zo + yi_[j] * W_;
                    float rs;
                    rs  = xw_[0] * row[xi_[0]];
                    rs += xw_[1] * row[xi_[1]];
                    rs += xw_[2] * row[xi_[2]];
                    rs += xw_[3] * row[xi_[3]];
                    acc += wzy * rs;
                }
            }
        }
    }
    out[idx] = acc * 0.125f;
}

extern "C" void kernel_launch(void* const* d_in, const int* in_sizes, int n_in,
                              void* d_out, int out_size, void* d_ws, size_t ws_size,
                              hipStream_t stream) {
    const float* feat = (const float*)d_in[0];
    const float* rois = (const float*)d_in[1];
    float* out = (float*)d_out;

    const size_t need = (size_t)NVOX * C_ * sizeof(unsigned short); // 201,326,592 B

    if (ws_size >= need) {
        unsigned short* ft = (unsigned short*)d_ws;
        // Phase 1: transpose. 2*24*128*8 = 49152 blocks.
        hipLaunchKernelGGL(transpose_chlast_fp16, dim3(49152), dim3(256), 0, stream,
                           feat, ft);
        // Phase 2: gather. 50176 cells * 16 lanes = 802816 threads = 3136 blocks.
        hipLaunchKernelGGL(roialign_gather_fp16, dim3(3136), dim3(256), 0, stream,
                           ft, rois, out);
    } else {
        int total = out_size;
        int blocks = (total + 255) / 256;
        hipLaunchKernelGGL(roialign3d_direct, dim3(blocks), dim3(256), 0, stream,
                           feat, rois, out, total);
    }
}